// Round 3
// baseline (584.422 us; speedup 1.0000x reference)
//
#include <hip/hip_runtime.h>

// Conv2d 32x128x56x56 -> 32x256x56x56, 3x3, pad 1, stride 1. fp32 I/O.
// Implicit GEMM, bf16 mfma_f32_16x16x32. K = (ci_hi, kh*kw, ci_lo).
//  - prep_x: NCHW fp32 -> NHWC bf16, fully vectorized (float4 in, uint4 out)
//    via LDS transpose tile 128ci x 64p, row stride 136 shorts (16B-aligned).
//  - prep_w: W2[step][co][ci_lo], step = ci_hi*9+khw -> A-frags load straight
//    global->reg, coalesced, L2-hot.
//  - conv: 128-thread blocks (2 waves), tile 128co x 112p, grid 1792
//    (7 independent blocks/CU -> overlapped staging latencies, small barrier
//    convoys). Per ci_hi: stage 4rows x 58cols x 32ci x tile once, then 9 khw
//    positions barrier-free (immediate LDS offsets). Wave: 4m x 7n MFMA.

#define CIN   128
#define COUT  256
#define HWID  56
#define IMG   (HWID*HWID)     // 3136
#define NIMG  32
#define CSTR  40              // Bs ci stride (shorts): 80B, 16B-aligned, ~2-way banks
#define BROW  (58*CSTR)       // Bs row stride (shorts)
#define XSTR  136             // prep_x LDS p-row stride (shorts): 272B, 16B-aligned

typedef __attribute__((ext_vector_type(8))) short short8;   // 8 bf16 = 4 VGPRs
typedef __attribute__((ext_vector_type(4))) float float4v;  // MFMA acc

__device__ __forceinline__ unsigned short f2bf(float f) {
    unsigned int u = __builtin_bit_cast(unsigned int, f);
    u += 0x7FFFu + ((u >> 16) & 1u);   // RNE
    return (unsigned short)(u >> 16);
}

// W2[((ci_hi*9 + kh*3 + kw)*256 + co)*32 + ci_lo] = bf16(w[co][ci_hi*32+ci_lo][kh][kw])
__global__ void prep_w_kernel(const float* __restrict__ w, unsigned short* __restrict__ W2) {
    int o = blockIdx.x * 256 + threadIdx.x;        // 294912 total
    int ci_lo = o & 31;
    int co    = (o >> 5) & 255;
    int s     = o >> 13;                           // 0..35
    int ci_hi = s / 9;
    int r9    = s - ci_hi * 9;                     // kh*3+kw
    W2[o] = f2bf(w[(co * CIN + ci_hi * 32 + ci_lo) * 9 + r9]);
}

// NCHW fp32 -> NHWC bf16. Tile: all 128 ci x 64 p. float4 reads, uint4 writes.
__global__ __launch_bounds__(256)
void prep_x_kernel(const float* __restrict__ x, unsigned short* __restrict__ X2) {
    __shared__ __align__(16) unsigned short Ls[64 * XSTR];   // [p][ci] 17408 B
    int b  = blockIdx.x;               // n*49 + pb
    int pb = b % 49;
    int n  = b / 49;
    int p0 = pb * 64;

    const float* src = x + (long)n * CIN * IMG + p0;
    #pragma unroll
    for (int it = 0; it < 8; ++it) {
        int flat = it * 256 + threadIdx.x;      // 0..2047
        int ci   = flat >> 4;
        int p4   = (flat & 15) * 4;
        float4 v = *(const float4*)(src + (long)ci * IMG + p4);  // 16B coalesced
        Ls[(p4 + 0) * XSTR + ci] = f2bf(v.x);
        Ls[(p4 + 1) * XSTR + ci] = f2bf(v.y);
        Ls[(p4 + 2) * XSTR + ci] = f2bf(v.z);
        Ls[(p4 + 3) * XSTR + ci] = f2bf(v.w);
    }
    __syncthreads();
    unsigned short* dst = X2 + ((long)n * IMG + p0) * CIN;
    #pragma unroll
    for (int it = 0; it < 4; ++it) {
        int flat = it * 256 + threadIdx.x;      // 0..1023
        int p    = flat >> 4;
        int c8   = (flat & 15) * 8;
        *(uint4*)(dst + (long)p * CIN + c8) = *(const uint4*)(&Ls[p * XSTR + c8]); // 16B coalesced
    }
}

__global__ __launch_bounds__(128, 4)
void conv_mfma_kernel(const unsigned short* __restrict__ X2,
                      const unsigned short* __restrict__ W2,
                      float* __restrict__ out) {
    __shared__ __align__(16) unsigned short Bs[4 * BROW];   // 4 x 58 x 40 ci: 18560 B

    const int tid  = threadIdx.x;       // 0..127
    const int lane = tid & 63;
    const int wv   = tid >> 6;          // 0..1 -> co offset wv*64
    const int l15  = lane & 15;
    const int quad = lane >> 4;

    const int bid   = blockIdx.x;       // 0..1791
    const int cb    = bid & 1;          // co half: cb*128
    const int pt    = bid >> 1;         // 0..895
    const int n_img = pt / 28;
    const int h0    = (pt % 28) * 2;    // output rows h0, h0+1

    // per-lane b-frag bases (short index into Bs), one per n-tile
    int boff[7];
    #pragma unroll
    for (int n = 0; n < 7; ++n) {
        int p    = n * 16 + l15;
        int prow = (p >= 56) ? 1 : 0;
        int pcol = p - prow * 56;
        boff[n]  = (prow * 58 + pcol) * CSTR + quad * 8;
    }

    // a-frag base: W2[step][co][ci_lo], co = cb*128 + wv*64 + m*16 + l15
    const unsigned short* wbase = W2 + (cb * 128 + wv * 64 + l15) * 32 + quad * 8;

    float4v acc[4][7];
    #pragma unroll
    for (int m = 0; m < 4; ++m)
        #pragma unroll
        for (int n = 0; n < 7; ++n)
            acc[m][n] = (float4v){0.f, 0.f, 0.f, 0.f};

    const unsigned short* xnb = X2 + (long)n_img * (IMG * CIN);

    for (int ci_hi = 0; ci_hi < 4; ++ci_hi) {
        __syncthreads();   // protect Bs from previous iteration's readers

        // ---- stage raw x tile: 4 rows x 58 cols x 32 ci, halo -> 0 ----
        #pragma unroll
        for (int it = 0; it < 8; ++it) {
            int idx = it * 128 + tid;      // 0..1023, valid < 928
            if (idx < 928) {
                int ci8 = idx & 3;
                int rc  = idx >> 2;        // r*58 + c, < 232
                int r = rc / 58;
                int c = rc - r * 58;
                int h = h0 - 1 + r;
                int w = c - 1;
                uint4 v = make_uint4(0u, 0u, 0u, 0u);
                if ((unsigned)h < 56u && (unsigned)w < 56u)
                    v = *(const uint4*)(xnb + ((h * HWID + w) * CIN + ci_hi * 32 + ci8 * 8));
                *(uint4*)(&Bs[rc * CSTR + ci8 * 8]) = v;
            }
        }
        __syncthreads();

        // ---- 9 khw positions, NO barriers (Bs read-only here) ----
        #pragma unroll
        for (int khw = 0; khw < 9; ++khw) {
            const int kh = khw / 3, kw = khw - (khw / 3) * 3;
            const int step = ci_hi * 9 + khw;
            short8 a[4], b[7];
            #pragma unroll
            for (int m = 0; m < 4; ++m)
                a[m] = *(const short8*)(wbase + step * 8192 + m * 512);
            #pragma unroll
            for (int n = 0; n < 7; ++n)
                b[n] = *(const short8*)(&Bs[boff[n] + (kh * 58 + kw) * CSTR]);
            #pragma unroll
            for (int m = 0; m < 4; ++m)
                #pragma unroll
                for (int n = 0; n < 7; ++n)
                    acc[m][n] = __builtin_amdgcn_mfma_f32_16x16x32_bf16(a[m], b[n], acc[m][n], 0, 0, 0);
        }
    }

    // ---- epilogue: C/D layout col(p)=lane&15, row(co)=quad*4+reg ----
    float* obase = out + (long)n_img * (COUT * IMG) + h0 * HWID;
    #pragma unroll
    for (int m = 0; m < 4; ++m) {
        #pragma unroll
        for (int r = 0; r < 4; ++r) {
            int co = cb * 128 + wv * 64 + m * 16 + quad * 4 + r;
            float* orow = obase + (long)co * IMG;
            #pragma unroll
            for (int n = 0; n < 7; ++n)
                orow[n * 16 + l15] = acc[m][n][r];
        }
    }
}

extern "C" void kernel_launch(void* const* d_in, const int* in_sizes, int n_in,
                              void* d_out, int out_size, void* d_ws, size_t ws_size,
                              hipStream_t stream) {
    const float* x  = (const float*)d_in[0];
    const float* wt = (const float*)d_in[1];
    float* out = (float*)d_out;

    unsigned short* X2 = (unsigned short*)d_ws;            // 12,845,056 shorts (NHWC bf16)
    unsigned short* W2 = X2 + (long)NIMG * CIN * IMG;      // 294,912 shorts

    prep_x_kernel<<<NIMG * 49, 256, 0, stream>>>(x, X2);
    prep_w_kernel<<<(COUT * CIN * 9) / 256, 256, 0, stream>>>(wt, W2);
    conv_mfma_kernel<<<1792, 128, 0, stream>>>(X2, W2, out);
}

// Round 4
// 207.004 us; speedup vs baseline: 2.8232x; 2.8232x over previous
//
#include <hip/hip_runtime.h>

// Conv2d 32x128x56x56 -> 32x256x56x56, 3x3, pad 1, stride 1. fp32 I/O.
// Implicit GEMM, bf16 mfma_f32_16x16x32. K = (ci_hi, kh*kw, ci_lo).
//  - prep_x: NCHW fp32 -> NHWC bf16 via PURE-REGISTER transpose (no LDS):
//    each thread loads 8 float4 (8 ci x 4 p), repacks, stores 4 uint4
//    (256B-contiguous NHWC stores per 16-lane group).
//  - prep_w: W2[step][co][ci_lo], step = ci_hi*9+khw -> A-frags straight
//    global->reg, coalesced, L2-hot.
//  - conv: 256 thr / 4 waves, tile 256co x 112p, __launch_bounds__(256,2)
//    (NOTE: (128,4) in R3 forced a 128-reg budget -> acc spill -> 2.2GB
//    scratch traffic, 5.5x slower. Keep the 256-reg budget.)
//    Register-prefetch of next ci_hi x-tile overlaps global latency with the
//    9-khw MFMA block. Staging addresses/masks hoisted (ci_hi-invariant).

#define CIN   128
#define COUT  256
#define HWID  56
#define IMG   (HWID*HWID)     // 3136
#define NIMG  32
#define CSTR  40              // Bs ci stride (shorts): 80B, 16B-aligned, ~2-way banks
#define BROW  (58*CSTR)       // Bs row stride (shorts)

typedef __attribute__((ext_vector_type(8))) short short8;   // 8 bf16 = 4 VGPRs
typedef __attribute__((ext_vector_type(4))) float float4v;  // MFMA acc

__device__ __forceinline__ unsigned short f2bf(float f) {
    unsigned int u = __builtin_bit_cast(unsigned int, f);
    u += 0x7FFFu + ((u >> 16) & 1u);   // RNE
    return (unsigned short)(u >> 16);
}

// W2[((ci_hi*9 + kh*3 + kw)*256 + co)*32 + ci_lo] = bf16(w[co][ci_hi*32+ci_lo][kh][kw])
__global__ void prep_w_kernel(const float* __restrict__ w, unsigned short* __restrict__ W2) {
    int o = blockIdx.x * 256 + threadIdx.x;        // 294912 total
    int ci_lo = o & 31;
    int co    = (o >> 5) & 255;
    int s     = o >> 13;                           // 0..35
    int ci_hi = s / 9;
    int r9    = s - ci_hi * 9;                     // kh*3+kw
    W2[o] = f2bf(w[(co * CIN + ci_hi * 32 + ci_lo) * 9 + r9]);
}

// NCHW fp32 -> NHWC bf16, register-only transpose. Block: 128 ci x 64 p.
__global__ __launch_bounds__(256)
void prep_x_kernel(const float* __restrict__ x, unsigned short* __restrict__ X2) {
    int b  = blockIdx.x;               // n*49 + pb
    int pb = b % 49;
    int n  = b / 49;
    int p0 = pb * 64;

    int t   = threadIdx.x;
    int ci8 = t & 15;                  // ci block: ci8*8 .. ci8*8+7
    int p4  = t >> 4;                  // p block: p0 + p4*4 .. +3

    const float* src = x + (long)n * CIN * IMG + p0 + p4 * 4 + (long)(ci8 * 8) * IMG;
    float4 v[8];
    #pragma unroll
    for (int j = 0; j < 8; ++j)
        v[j] = *(const float4*)(src + (long)j * IMG);

    unsigned short* dst = X2 + ((long)n * IMG + p0 + p4 * 4) * CIN + ci8 * 8;
    #pragma unroll
    for (int k = 0; k < 4; ++k) {
        float e[8] = {v[0][k], v[1][k], v[2][k], v[3][k], v[4][k], v[5][k], v[6][k], v[7][k]};
        ushort4 o;
        o.x = (unsigned short)(f2bf(e[0]) | ((unsigned)f2bf(e[1]) << 16) & 0xFFFF0000u);
        // build two shorts per uint explicitly
        unsigned int u0 = (unsigned)f2bf(e[0]) | ((unsigned)f2bf(e[1]) << 16);
        unsigned int u1 = (unsigned)f2bf(e[2]) | ((unsigned)f2bf(e[3]) << 16);
        unsigned int u2 = (unsigned)f2bf(e[4]) | ((unsigned)f2bf(e[5]) << 16);
        unsigned int u3 = (unsigned)f2bf(e[6]) | ((unsigned)f2bf(e[7]) << 16);
        *(uint4*)(dst + (long)k * CIN) = make_uint4(u0, u1, u2, u3);
    }
}

__global__ __launch_bounds__(256, 2)
void conv_mfma_kernel(const unsigned short* __restrict__ X2,
                      const unsigned short* __restrict__ W2,
                      float* __restrict__ out) {
    __shared__ __align__(16) unsigned short Bs[4 * BROW];   // 4 x 58 x 40 ci: 18560 B

    const int tid  = threadIdx.x;
    const int lane = tid & 63;
    const int wv   = tid >> 6;
    const int l15  = lane & 15;
    const int quad = lane >> 4;

    const int pt    = blockIdx.x;      // 0..895
    const int n_img = pt / 28;
    const int h0    = (pt % 28) * 2;   // output rows h0, h0+1

    // per-lane b-frag bases (short index into Bs), one per n-tile
    int boff[7];
    #pragma unroll
    for (int n = 0; n < 7; ++n) {
        int p    = n * 16 + l15;
        int prow = (p >= 56) ? 1 : 0;
        int pcol = p - prow * 56;
        boff[n]  = (prow * 58 + pcol) * CSTR + quad * 8;
    }

    // a-frag base: W2[step][co][ci_lo], co = wv*64 + m*16 + l15
    const unsigned short* wbase = W2 + (wv * 64 + l15) * 32 + quad * 8;

    // ---- hoisted staging geometry (ci_hi-invariant) ----
    const unsigned short* xnb = X2 + (long)n_img * (IMG * CIN);
    const unsigned short* gsrc[4];   // global src (ci_hi=0), or null-masked
    int  ldst[4];                    // Bs short-offset
    bool gval[4];
    #pragma unroll
    for (int it = 0; it < 4; ++it) {
        int idx = it * 256 + tid;      // 0..1023, valid < 928
        int ci8 = idx & 3;
        int rc  = idx >> 2;            // r*58 + c, < 232
        int r = rc / 58;
        int c = rc - r * 58;
        int h = h0 - 1 + r;
        int w = c - 1;
        gval[it] = (idx < 928) && ((unsigned)h < 56u) && ((unsigned)w < 56u);
        gsrc[it] = xnb + ((h * HWID + w) * CIN + ci8 * 8);
        ldst[it] = rc * CSTR + ci8 * 8;
        if (idx >= 928) ldst[it] = 0;  // clamp (will store zeros harmlessly? no!)
    }
    // NOTE: idx>=928 lanes must not clobber Bs[0]; mask stores below.
    bool sval[4];
    #pragma unroll
    for (int it = 0; it < 4; ++it) sval[it] = ((it * 256 + tid) < 928);

    float4v acc[4][7];
    #pragma unroll
    for (int m = 0; m < 4; ++m)
        #pragma unroll
        for (int n = 0; n < 7; ++n)
            acc[m][n] = (float4v){0.f, 0.f, 0.f, 0.f};

    // ---- prefetch tile 0 ----
    uint4 pre[4];
    #pragma unroll
    for (int it = 0; it < 4; ++it)
        pre[it] = gval[it] ? *(const uint4*)(gsrc[it]) : make_uint4(0u, 0u, 0u, 0u);

    for (int ci_hi = 0; ci_hi < 4; ++ci_hi) {
        __syncthreads();   // previous iteration's readers done with Bs

        #pragma unroll
        for (int it = 0; it < 4; ++it)
            if (sval[it]) *(uint4*)(&Bs[ldst[it]]) = pre[it];

        __syncthreads();

        // issue next tile's global loads; vmcnt waited only at next store
        if (ci_hi < 3) {
            #pragma unroll
            for (int it = 0; it < 4; ++it)
                pre[it] = gval[it] ? *(const uint4*)(gsrc[it] + (ci_hi + 1) * 32)
                                   : make_uint4(0u, 0u, 0u, 0u);
        }

        // ---- 9 khw positions, barrier-free ----
        #pragma unroll
        for (int khw = 0; khw < 9; ++khw) {
            const int kh = khw / 3, kw = khw - (khw / 3) * 3;
            const int step = ci_hi * 9 + khw;
            short8 a[4], b[7];
            #pragma unroll
            for (int m = 0; m < 4; ++m)
                a[m] = *(const short8*)(wbase + step * 8192 + m * 512);
            #pragma unroll
            for (int n = 0; n < 7; ++n)
                b[n] = *(const short8*)(&Bs[boff[n] + (kh * 58 + kw) * CSTR]);
            #pragma unroll
            for (int m = 0; m < 4; ++m)
                #pragma unroll
                for (int n = 0; n < 7; ++n)
                    acc[m][n] = __builtin_amdgcn_mfma_f32_16x16x32_bf16(a[m], b[n], acc[m][n], 0, 0, 0);
        }
    }

    // ---- epilogue: C/D layout col(p)=lane&15, row(co)=quad*4+reg ----
    float* obase = out + (long)n_img * (COUT * IMG) + h0 * HWID;
    #pragma unroll
    for (int m = 0; m < 4; ++m) {
        #pragma unroll
        for (int r = 0; r < 4; ++r) {
            int co = wv * 64 + m * 16 + quad * 4 + r;
            float* orow = obase + (long)co * IMG;
            #pragma unroll
            for (int n = 0; n < 7; ++n)
                orow[n * 16 + l15] = acc[m][n][r];
        }
    }
}

extern "C" void kernel_launch(void* const* d_in, const int* in_sizes, int n_in,
                              void* d_out, int out_size, void* d_ws, size_t ws_size,
                              hipStream_t stream) {
    const float* x  = (const float*)d_in[0];
    const float* wt = (const float*)d_in[1];
    float* out = (float*)d_out;

    unsigned short* X2 = (unsigned short*)d_ws;            // 12,845,056 shorts (NHWC bf16)
    unsigned short* W2 = X2 + (long)NIMG * CIN * IMG;      // 294,912 shorts

    prep_x_kernel<<<NIMG * 49, 256, 0, stream>>>(x, X2);
    prep_w_kernel<<<(COUT * CIN * 9) / 256, 256, 0, stream>>>(wt, W2);
    conv_mfma_kernel<<<896, 256, 0, stream>>>(X2, W2, out);
}